// Round 1
// baseline (875.393 us; speedup 1.0000x reference)
//
#include <hip/hip_runtime.h>
#include <math.h>

#define NROWS 65536          // 64*32*32
#define DIM   256
#define KCB   1024
#define TM    16             // rows per block
#define QOFF  (NROWS * DIM)  // 16777216: quantized elems, then loss, then indices
#define IDXOFF (QOFF + 1)

// ws float layout
#define WS_DMIN 0
#define WS_PLP  1
#define WS_AVGP 4            // 1024 floats
#define WS_C2   1028         // 1024 floats (16B aligned: 1028*4=4112)

// LDS float offsets (dynamic shared)
#define L_CT  0               // 1024 * 16 codebook slab, swizzled
#define L_XT  16384           // 16 * 16 x slab
#define L_X2  16640           // 16 row norms
#define L_RDD 16656           // [2][16] per-half dmin
#define L_RDK 16688           // [2][16] per-half argmin (int)
#define L_RT1 16720           // [2][16]
#define L_RT2 16752           // [2][16]
#define L_AVG 16784           // 1024 block avg_prob sums
#define L_SCL 17808           // 2 scalars
#define SMEM_FLOATS 17810
#define SMEM_BYTES  (SMEM_FLOATS * 4)

extern __shared__ float smem[];

__global__ __launch_bounds__(256) void c2_kernel(const float* __restrict__ cb,
                                                 float* __restrict__ ws) {
    int k = blockIdx.x * 256 + threadIdx.x;
    const float4* row = (const float4*)(cb + (size_t)k * DIM);
    float s = 0.f;
#pragma unroll 8
    for (int i = 0; i < DIM / 4; ++i) {
        float4 v = row[i];
        s += v.x * v.x + v.y * v.y + v.z * v.z + v.w * v.w;
    }
    ws[WS_C2 + k] = s;
}

__global__ __launch_bounds__(256) void vq_main(const float* __restrict__ x,
                                               const float* __restrict__ cb,
                                               float* __restrict__ ws,
                                               float* __restrict__ out) {
    float* ctile = smem + L_CT;
    float* xtile = smem + L_XT;
    float* x2l   = smem + L_X2;
    float* redd  = smem + L_RDD;
    int*   redk  = (int*)(smem + L_RDK);
    float* redt1 = smem + L_RT1;
    float* redt2 = smem + L_RT2;
    float* avgp  = smem + L_AVG;
    float* bscal = smem + L_SCL;

    const int tid = threadIdx.x;
    const int w   = tid >> 6;        // wave 0..3
    const int l   = tid & 63;        // lane
    const int rg  = w >> 1;          // rowgroup: rows rg*8 .. rg*8+7
    const int h   = w & 1;           // column half: cols h*512 .. h*512+511
    const int R0  = blockIdx.x * TM;

    // zero block accumulators
    for (int t = tid; t < 1024; t += 256) avgp[t] = 0.f;
    if (tid < 2) bscal[tid] = 0.f;

    // deterministic per-row |x|^2 (threads 0..15, one row each, sequential)
    if (tid < 16) {
        const float4* px = (const float4*)(x + (size_t)(R0 + tid) * DIM);
        float s = 0.f;
#pragma unroll 16
        for (int q = 0; q < DIM / 4; ++q) {
            float4 v = px[q];
            s += v.x * v.x + v.y * v.y + v.z * v.z + v.w * v.w;
        }
        x2l[tid] = s;
    }

    float acc[8][8];
#pragma unroll
    for (int rr = 0; rr < 8; ++rr)
#pragma unroll
        for (int j = 0; j < 8; ++j) acc[rr][j] = 0.f;

    const int slot_l = (l >> 1) & 3;   // read-side swizzle (k = ...64j + l -> (k>>1)&3 == (l>>1)&3)

    // ---- GEMM: dot(x_row, c_k) over d in 16-wide slabs ----
    for (int s = 0; s < DIM / 16; ++s) {
        const int dds = s * 16;
        // stage codebook slab: 1024 rows x 16 dd, swizzled f4 slots
#pragma unroll
        for (int m = 0; m < 4; ++m) {
            int kk = tid + (m << 8);
            const float4* src = (const float4*)(cb + (size_t)kk * DIM + dds);
            float4 v0 = src[0], v1 = src[1], v2 = src[2], v3 = src[3];
            float* dst = ctile + (kk << 4);
            int sw = (kk >> 1) & 3;
            *(float4*)(dst + (((0 ^ sw)) << 2)) = v0;
            *(float4*)(dst + (((1 ^ sw)) << 2)) = v1;
            *(float4*)(dst + (((2 ^ sw)) << 2)) = v2;
            *(float4*)(dst + (((3 ^ sw)) << 2)) = v3;
        }
        // stage x slab: 16 rows x 16 dd
        if (tid < 64) {
            int r = tid >> 2, p = tid & 3;
            *(float4*)(xtile + r * 16 + p * 4) =
                *(const float4*)(x + (size_t)(R0 + r) * DIM + dds + p * 4);
        }
        __syncthreads();

        const float* xrow = xtile + (rg * 8) * 16;
#pragma unroll
        for (int g = 0; g < 4; ++g) {
            float4 b[8];
#pragma unroll
            for (int j = 0; j < 8; ++j) {
                int k = h * 512 + j * 64 + l;
                b[j] = *(const float4*)(ctile + (k << 4) + ((g ^ slot_l) << 2));
            }
#pragma unroll
            for (int rr = 0; rr < 8; ++rr) {
                float4 a = *(const float4*)(xrow + rr * 16 + (g << 2));  // broadcast
#pragma unroll
                for (int j = 0; j < 8; ++j) {
                    acc[rr][j] = fmaf(a.x, b[j].x, acc[rr][j]);
                    acc[rr][j] = fmaf(a.y, b[j].y, acc[rr][j]);
                    acc[rr][j] = fmaf(a.z, b[j].z, acc[rr][j]);
                    acc[rr][j] = fmaf(a.w, b[j].w, acc[rr][j]);
                }
            }
        }
        __syncthreads();
    }

    // ---- distances, matching ref association: (x2 - 2ab) + c2 ----
    float c2v[8];
#pragma unroll
    for (int j = 0; j < 8; ++j) c2v[j] = ws[WS_C2 + h * 512 + j * 64 + l];
#pragma unroll
    for (int rr = 0; rr < 8; ++rr) {
        float x2r = x2l[rg * 8 + rr];
#pragma unroll
        for (int j = 0; j < 8; ++j) {
            float t = 2.0f * acc[rr][j];
            acc[rr][j] = (x2r - t) + c2v[j];
        }
    }

    // ---- argmin (first-index tie-break like jnp.argmin) ----
    float dminf[8];
    int   kminf[8];
#pragma unroll
    for (int rr = 0; rr < 8; ++rr) {
        float md = acc[rr][0];
        int   mk = h * 512 + l;
#pragma unroll
        for (int j = 1; j < 8; ++j) {
            int k = h * 512 + j * 64 + l;
            if (acc[rr][j] < md) { md = acc[rr][j]; mk = k; }
        }
#pragma unroll
        for (int off = 32; off; off >>= 1) {
            float od = __shfl_xor(md, off);
            int   ok = __shfl_xor(mk, off);
            if (od < md || (od == md && ok < mk)) { md = od; mk = ok; }
        }
        if (l == 0) { redd[h * 16 + rg * 8 + rr] = md; redk[h * 16 + rg * 8 + rr] = mk; }
        dminf[rr] = md; kminf[rr] = mk;
    }
    __syncthreads();
#pragma unroll
    for (int rr = 0; rr < 8; ++rr) {
        int row = rg * 8 + rr;
        float d0 = redd[row], d1 = redd[16 + row];
        int   k0 = redk[row], k1 = redk[16 + row];
        if (d1 < d0 || (d1 == d0 && k1 < k0)) { dminf[rr] = d1; kminf[rr] = k1; }
        else                                   { dminf[rr] = d0; kminf[rr] = k0; }
    }

    // ---- softmax stats: T1 = sum e^{z'}, T2 = sum e^{z'} z', z' = -100(d - dmin) ----
    float T1[8], T2[8];
#pragma unroll
    for (int rr = 0; rr < 8; ++rr) {
        float t1 = 0.f, t2 = 0.f;
#pragma unroll
        for (int j = 0; j < 8; ++j) {
            float zp = -100.0f * (acc[rr][j] - dminf[rr]);
            float e  = __expf(zp);
            acc[rr][j] = e;                 // keep e for avg_probs
            t1 += e;
            t2 += e * zp;
        }
#pragma unroll
        for (int off = 32; off; off >>= 1) {
            t1 += __shfl_xor(t1, off);
            t2 += __shfl_xor(t2, off);
        }
        if (l == 0) { redt1[h * 16 + rg * 8 + rr] = t1; redt2[h * 16 + rg * 8 + rr] = t2; }
    }
    __syncthreads();
#pragma unroll
    for (int rr = 0; rr < 8; ++rr) {
        int row = rg * 8 + rr;
        T1[rr] = redt1[row] + redt1[16 + row];
        T2[rr] = redt2[row] + redt2[16 + row];
    }

    // ---- avg_probs: sum p over this thread's 8 rows, per column ----
    float rT1[8];
#pragma unroll
    for (int rr = 0; rr < 8; ++rr) rT1[rr] = 1.0f / T1[rr];
#pragma unroll
    for (int j = 0; j < 8; ++j) {
        float ps = 0.f;
#pragma unroll
        for (int rr = 0; rr < 8; ++rr) ps += acc[rr][j] * rT1[rr];
        atomicAdd(&avgp[h * 512 + j * 64 + l], ps);
    }

    // ---- per-row scalar losses + indices (one rep per rowgroup) ----
    if (h == 0 && l == 0) {
        float sd = 0.f, sp = 0.f;
#pragma unroll
        for (int rr = 0; rr < 8; ++rr) {
            sd += dminf[rr];
            sp += T2[rr] * rT1[rr] - logf(T1[rr]);   // sum p*logp for the row
            out[IDXOFF + R0 + rg * 8 + rr] = (float)kminf[rr];
        }
        atomicAdd(&bscal[0], sd);
        atomicAdd(&bscal[1], sp);
    }

    // ---- quantized output: wave w copies rows w*4..w*4+3 (rr = h*4+i) ----
#pragma unroll
    for (int i = 0; i < 4; ++i) {
        int k, rowloc;
        if (h == 0) { k = kminf[i];     rowloc = rg * 8 + i; }
        else        { k = kminf[4 + i]; rowloc = rg * 8 + 4 + i; }
        float4 q = *(const float4*)(cb + (size_t)k * DIM + (l << 2));
        *(float4*)(out + (size_t)(R0 + rowloc) * DIM + (l << 2)) = q;
    }

    __syncthreads();
    for (int t = tid; t < 1024; t += 256) atomicAdd(ws + WS_AVGP + t, avgp[t]);
    if (tid == 0) {
        atomicAdd(ws + WS_DMIN, bscal[0]);
        atomicAdd(ws + WS_PLP,  bscal[1]);
    }
}

__global__ __launch_bounds__(256) void vq_finalize(const float* __restrict__ ws,
                                                   float* __restrict__ out) {
    __shared__ float red[4];
    int tid = threadIdx.x;
    float part = 0.f;
    for (int k = tid; k < 1024; k += 256) {
        float ap = ws[WS_AVGP + k] * (1.0f / 65536.0f);
        part += ap * logf(ap + 1e-5f);
    }
#pragma unroll
    for (int off = 32; off; off >>= 1) part += __shfl_xor(part, off);
    if ((tid & 63) == 0) red[tid >> 6] = part;
    __syncthreads();
    if (tid == 0) {
        float sum_aplog    = red[0] + red[1] + red[2] + red[3];
        float avg_entropy  = -sum_aplog;
        float sample_entropy = -ws[WS_PLP] * (1.0f / 65536.0f);
        float entropy_loss = (sample_entropy - avg_entropy) * 0.1f;
        float eq = 1.25f * ws[WS_DMIN] * (1.0f / ((float)NROWS * (float)DIM));
        out[QOFF] = eq + entropy_loss;
    }
}

extern "C" void kernel_launch(void* const* d_in, const int* in_sizes, int n_in,
                              void* d_out, int out_size, void* d_ws, size_t ws_size,
                              hipStream_t stream) {
    const float* x  = (const float*)d_in[0];
    const float* cb = (const float*)d_in[1];
    float* out = (float*)d_out;
    float* ws  = (float*)d_ws;

    // zero accumulator region of ws (scalars + avg_probs); c2 region is overwritten
    hipMemsetAsync(d_ws, 0, (WS_C2) * sizeof(float), stream);

    c2_kernel<<<KCB / 256, 256, 0, stream>>>(cb, ws);

    hipFuncSetAttribute((const void*)vq_main,
                        hipFuncAttributeMaxDynamicSharedMemorySize, SMEM_BYTES);
    vq_main<<<NROWS / TM, 256, SMEM_BYTES, stream>>>(x, cb, ws, out);

    vq_finalize<<<1, 256, 0, stream>>>(ws, out);
}

// Round 3
// 398.561 us; speedup vs baseline: 2.1964x; 2.1964x over previous
//
#include <hip/hip_runtime.h>
#include <math.h>

#define NROWS 65536
#define DIM   256
#define KCB   1024
#define TM    64              // rows per block
#define QOFF  (NROWS * DIM)
#define IDXOFF (QOFF + 1)

// ws float layout
#define WS_DMIN 0
#define WS_PLP  1
#define WS_AVGP 4             // 1024 floats
#define WS_C2   1028          // 1024 floats
#define WS_CBH  2052          // 1024*256 ushort = 131072 floats
#define WS_CBL  (WS_CBH + 131072)
#define WS_TOTAL (WS_CBL + 131072)

#define DELTA 1e-2f

typedef __attribute__((ext_vector_type(8))) __bf16 bf16x8;
typedef __attribute__((ext_vector_type(4))) float  f32x4;
typedef __attribute__((ext_vector_type(8))) unsigned short u16x8;
typedef __attribute__((ext_vector_type(4))) unsigned short u16x4;

#define SWZ(c) ((((c)&3))^(((c)>>2)&3))

// LDS byte offsets
#define LB_B   0        // 2 x 65536 (hi at +0, lo at +32768 within each buf)
#define LB_X   131072   // 2 x 8192  (hi at +0, lo at +4096 within each buf)
#define SMEM_BYTES 147456
// epilogue aliases (float index into smem, within first B buffer)
#define EP_REDD 0
#define EP_REDK 512
#define EP_RT1  1024
#define EP_RT2  1536
#define EP_GMIN 2048
#define EP_CNT  2112
#define EP_CAND 2176
#define EP_CEX  3200
#define EP_R1F  4224
#define EP_SP   4288
#define EP_KFIN 4352
#define EP_DFIN 4416
#define EP_AVGP 4480   // 1024

extern __shared__ char smem_raw[];

__device__ __forceinline__ unsigned short f2bf(float f) {
    unsigned u = __float_as_uint(f);
    u += 0x7fffu + ((u >> 16) & 1u);
    return (unsigned short)(u >> 16);
}
__device__ __forceinline__ float bf2f(unsigned short h) {
    return __uint_as_float(((unsigned)h) << 16);
}

// ---------------- c2: EXACT round-1 association (sequential float4 chain) ----------------
__global__ __launch_bounds__(256) void c2_kernel(const float* __restrict__ cb,
                                                 float* __restrict__ ws) {
    int k = blockIdx.x * 256 + threadIdx.x;
    const float4* row = (const float4*)(cb + (size_t)k * DIM);
    float s = 0.f;
#pragma unroll 8
    for (int i = 0; i < DIM / 4; ++i) {
        float4 v = row[i];
        s += v.x * v.x + v.y * v.y + v.z * v.z + v.w * v.w;
    }
    ws[WS_C2 + k] = s;
}

// ---------------- codebook bf16 hi/lo split ----------------
__global__ __launch_bounds__(256) void cvt_cb_kernel(const float* __restrict__ cb,
                                                     float* __restrict__ ws) {
    int w = threadIdx.x >> 6, lane = threadIdx.x & 63;
    int k = blockIdx.x * 4 + w;
    unsigned short* cbh = (unsigned short*)(ws + WS_CBH);
    unsigned short* cbl = (unsigned short*)(ws + WS_CBL);
    float4 v = *((const float4*)(cb + ((size_t)k << 8)) + lane);
    float f[4] = {v.x, v.y, v.z, v.w};
    u16x4 ho, lo;
#pragma unroll
    for (int i = 0; i < 4; ++i) {
        unsigned short hi = f2bf(f[i]);
        ho[i] = hi;
        lo[i] = f2bf(f[i] - bf2f(hi));
    }
    ((u16x4*)(cbh + ((size_t)k << 8)))[lane] = ho;
    ((u16x4*)(cbl + ((size_t)k << 8)))[lane] = lo;
}

// ---------------- staging helpers ----------------
__device__ __forceinline__ void stage_sub(const unsigned short* cbh, const unsigned short* cbl,
                                          char* bbase, int sub, int w, int lane) {
    int kc = sub >> 1, h = sub & 1;
    int d0 = kc << 5, cg0 = h << 9;
#pragma unroll
    for (int j = 0; j < 8; ++j) {
        int t = (w << 3) + j;
        int arr = t >> 5, o32 = t & 31;
        char* lds = bbase + (arr << 15) + (o32 << 10);
        int c = (o32 << 4) + (lane >> 2);
        int s = (lane & 3) ^ SWZ(c);
        const unsigned short* src = (arr ? cbl : cbh) + (((size_t)(cg0 + c)) << 8) + d0 + (s << 3);
        __builtin_amdgcn_global_load_lds((const __attribute__((address_space(1))) unsigned int*)src,
                                         (__attribute__((address_space(3))) unsigned int*)lds,
                                         16, 0, 0);
    }
}

__device__ __forceinline__ void convert_x_chunk(const float* __restrict__ x, char* xbase,
                                                int R0, int kc, int tid) {
    int u = tid & 255, arr = tid >> 8;
    int row = u >> 2, sl = u & 3;
    const float* src = x + (((size_t)(R0 + row)) << 8) + (kc << 5) + (sl << 3);
    float4 v0 = *(const float4*)src, v1 = *(const float4*)(src + 4);
    float f[8] = {v0.x, v0.y, v0.z, v0.w, v1.x, v1.y, v1.z, v1.w};
    u16x8 o;
#pragma unroll
    for (int i = 0; i < 8; ++i) {
        unsigned short hi = f2bf(f[i]);
        o[i] = arr ? f2bf(f[i] - bf2f(hi)) : hi;
    }
    *(u16x8*)(xbase + (arr << 12) + row * 64 + ((sl ^ SWZ(row)) << 4)) = o;
}

// ---------------- main fused kernel ----------------
__global__ __launch_bounds__(512, 2) void vq_main(const float* __restrict__ x,
                                                  const float* __restrict__ cb,
                                                  float* __restrict__ ws,
                                                  float* __restrict__ out) {
    const int tid  = threadIdx.x;
    const int w    = tid >> 6;
    const int lane = tid & 63;
    const int m    = lane & 15;
    const int q    = lane >> 4;
    const int R0   = blockIdx.x * TM;

    const unsigned short* cbh = (const unsigned short*)(ws + WS_CBH);
    const unsigned short* cbl = (const unsigned short*)(ws + WS_CBL);
    float* epi = (float*)smem_raw;

    f32x4 acc[4][8];
#pragma unroll
    for (int a = 0; a < 4; ++a)
#pragma unroll
        for (int b = 0; b < 8; ++b) acc[a][b] = (f32x4)0.f;

    // prologue: stage sub 0, convert x chunk 0
    stage_sub(cbh, cbl, smem_raw + LB_B, 0, w, lane);
    convert_x_chunk(x, smem_raw + LB_X, R0, 0, tid);

    bf16x8 ah[4], al[4];

    for (int sub = 0; sub < 16; ++sub) {
        __syncthreads();
        if (sub < 15)
            stage_sub(cbh, cbl, smem_raw + LB_B + (((sub + 1) & 1) << 16), sub + 1, w, lane);
        if ((sub & 1) == 1 && sub < 15)
            convert_x_chunk(x, smem_raw + LB_X + ((((sub >> 1) + 1) & 1) << 13),
                            R0, (sub >> 1) + 1, tid);

        const int kc = sub >> 1, h = sub & 1;
        const char* bbase = smem_raw + LB_B + ((sub & 1) << 16);
        if (h == 0) {
            const char* xbase = smem_raw + LB_X + ((kc & 1) << 13);
#pragma unroll
            for (int rt = 0; rt < 4; ++rt) {
                int row = (rt << 4) + m;
                int off = row * 64 + ((q ^ SWZ(row)) << 4);
                ah[rt] = *(const bf16x8*)(xbase + off);
                al[rt] = *(const bf16x8*)(xbase + 4096 + off);
            }
        }
#pragma unroll
        for (int ct = 0; ct < 4; ++ct) {
            int c = (w << 6) + (ct << 4) + m;
            int off = c * 64 + ((q ^ SWZ(c)) << 4);
            bf16x8 bh = *(const bf16x8*)(bbase + off);
            bf16x8 bl = *(const bf16x8*)(bbase + 32768 + off);
            int cg = (h << 2) + ct;
#pragma unroll
            for (int rt = 0; rt < 4; ++rt) {
                acc[rt][cg] = __builtin_amdgcn_mfma_f32_16x16x32_bf16(ah[rt], bh, acc[rt][cg], 0, 0, 0);
                acc[rt][cg] = __builtin_amdgcn_mfma_f32_16x16x32_bf16(ah[rt], bl, acc[rt][cg], 0, 0, 0);
                acc[rt][cg] = __builtin_amdgcn_mfma_f32_16x16x32_bf16(al[rt], bh, acc[rt][cg], 0, 0, 0);
            }
        }
    }
    __syncthreads();

    // ================= epilogue (aliases LDS over B buffers) =================
    // E0: zero block accumulators; g = c2 - 2*acc (approx grid); per-wave per-row argmin
    if (tid < 64) ((int*)(epi + EP_CNT))[tid] = 0;
#pragma unroll
    for (int t = tid; t < 1024; t += 512) epi[EP_AVGP + t] = 0.f;

    float c2v[8];
#pragma unroll
    for (int cg = 0; cg < 8; ++cg) {
        int col = ((cg >> 2) << 9) + (w << 6) + ((cg & 3) << 4) + m;
        c2v[cg] = ws[WS_C2 + col];
    }
#pragma unroll
    for (int rt = 0; rt < 4; ++rt) {
#pragma unroll
        for (int reg = 0; reg < 4; ++reg) {
            int row = (rt << 4) + (q << 2) + reg;
            float md = 3.0e38f; int mk = 0;
#pragma unroll
            for (int cg = 0; cg < 8; ++cg) {
                float g = c2v[cg] - 2.0f * acc[rt][cg][reg];
                acc[rt][cg][reg] = g;
                int col = ((cg >> 2) << 9) + (w << 6) + ((cg & 3) << 4) + m;
                if (g < md) { md = g; mk = col; }
            }
#pragma unroll
            for (int off = 1; off <= 8; off <<= 1) {
                float od = __shfl_xor(md, off, 64);
                int   ok = __shfl_xor(mk, off, 64);
                if (od < md || (od == md && ok < mk)) { md = od; mk = ok; }
            }
            if (m == 0) {
                epi[EP_REDD + (w << 6) + row] = md;
                ((int*)(epi + EP_REDK))[(w << 6) + row] = mk;
            }
        }
    }
    __syncthreads();

    // E1: cross-wave min per row (approx grid, only used as softmax shift + screen ref)
    if (tid < 64) {
        float gm = 3.0e38f;
#pragma unroll
        for (int wv = 0; wv < 8; ++wv) {
            float d = epi[EP_REDD + (wv << 6) + tid];
            if (d < gm) gm = d;
        }
        epi[EP_GMIN + tid] = gm;
    }
    __syncthreads();

    // E2: exp pass + candidate collection + per-wave T1/T2
    {
        int* cnt  = (int*)(epi + EP_CNT);
        int* cand = (int*)(epi + EP_CAND);
#pragma unroll
        for (int rt = 0; rt < 4; ++rt) {
#pragma unroll
            for (int reg = 0; reg < 4; ++reg) {
                int row = (rt << 4) + (q << 2) + reg;
                float gm = epi[EP_GMIN + row];
                float t1 = 0.f, t2 = 0.f;
#pragma unroll
                for (int cg = 0; cg < 8; ++cg) {
                    float g = acc[rt][cg][reg];
                    if (g < gm + DELTA) {
                        int col = ((cg >> 2) << 9) + (w << 6) + ((cg & 3) << 4) + m;
                        int pos = atomicAdd(&cnt[row], 1);
                        if (pos < 16) cand[(row << 4) + pos] = col;
                    }
                    float z = -100.0f * (g - gm);
                    float e = __expf(z);
                    acc[rt][cg][reg] = e;
                    t1 += e;
                    t2 += e * z;
                }
#pragma unroll
                for (int off = 1; off <= 8; off <<= 1) {
                    t1 += __shfl_xor(t1, off, 64);
                    t2 += __shfl_xor(t2, off, 64);
                }
                if (m == 0) {
                    epi[EP_RT1 + (w << 6) + row] = t1;
                    epi[EP_RT2 + (w << 6) + row] = t2;
                }
            }
        }
    }
    __syncthreads();

    // E3: finalize per-row softmax stats
    if (tid < 64) {
        float T1 = 0.f, T2 = 0.f;
#pragma unroll
        for (int wv = 0; wv < 8; ++wv) {
            T1 += epi[EP_RT1 + (wv << 6) + tid];
            T2 += epi[EP_RT2 + (wv << 6) + tid];
        }
        float r1 = 1.0f / T1;
        epi[EP_R1F + tid] = r1;
        epi[EP_SP + tid]  = T2 * r1 - logf(T1);
    }
    __syncthreads();

    // E4a: avg_probs column sums
    {
        float r1v[4][4];
#pragma unroll
        for (int rt = 0; rt < 4; ++rt)
#pragma unroll
            for (int reg = 0; reg < 4; ++reg)
                r1v[rt][reg] = epi[EP_R1F + (rt << 4) + (q << 2) + reg];
#pragma unroll
        for (int cg = 0; cg < 8; ++cg) {
            float s = 0.f;
#pragma unroll
            for (int rt = 0; rt < 4; ++rt)
#pragma unroll
                for (int reg = 0; reg < 4; ++reg)
                    s += acc[rt][cg][reg] * r1v[rt][reg];
            s += __shfl_xor(s, 16, 64);
            s += __shfl_xor(s, 32, 64);
            if (lane < 16) {
                int col = ((cg >> 2) << 9) + (w << 6) + ((cg & 3) << 4) + m;
                epi[EP_AVGP + col] += s;
            }
        }
    }
    // E4b: candidate refinement on the EXACT round-1 / np rounding grid:
    //      d = (x2 - 2*ab) + c2, ab = sequential fmaf chain d=0..255,
    //      x2 = round-1 source expression, c2 from round-1 c2_kernel.
    {
        int* cnt  = (int*)(epi + EP_CNT);
        int* cand = (int*)(epi + EP_CAND);
        int r = tid >> 3;
        int n = cnt[r]; if (n > 16) n = 16;
        for (int i = tid & 7; i < n; i += 8) {
            int k = cand[(r << 4) + i];
            const float4* ax = (const float4*)(x  + (((size_t)(R0 + r)) << 8));
            const float4* bx = (const float4*)(cb + (((size_t)k) << 8));
            float ab = 0.f, x2 = 0.f;
            for (int d4 = 0; d4 < 64; ++d4) {
                float4 a = ax[d4], b = bx[d4];
                ab = fmaf(a.x, b.x, ab);
                ab = fmaf(a.y, b.y, ab);
                ab = fmaf(a.z, b.z, ab);
                ab = fmaf(a.w, b.w, ab);
                x2 += a.x * a.x + a.y * a.y + a.z * a.z + a.w * a.w;
            }
            float t = 2.0f * ab;
            epi[EP_CEX + (r << 4) + i] = (x2 - t) + ws[WS_C2 + k];
        }
    }
    __syncthreads();

    // E5: final per-row selection (min d, lowest-index tie-break) + index output
    if (tid < 64) {
        int* cnt  = (int*)(epi + EP_CNT);
        int* cand = (int*)(epi + EP_CAND);
        int n = cnt[tid]; if (n > 16) n = 16;
        float bd = epi[EP_CEX + (tid << 4)];
        int   bk = cand[(tid << 4)];
        for (int i = 1; i < n; ++i) {
            float d = epi[EP_CEX + (tid << 4) + i];
            int   k = cand[(tid << 4) + i];
            if (d < bd || (d == bd && k < bk)) { bd = d; bk = k; }
        }
        ((int*)(epi + EP_KFIN))[tid] = bk;
        epi[EP_DFIN + tid] = bd;
        out[IDXOFF + R0 + tid] = (float)bk;
    }
    __syncthreads();

    // E6: quantized gather, global accumulators
#pragma unroll
    for (int rr = 0; rr < 8; ++rr) {
        int r = (w << 3) + rr;
        int k = ((int*)(epi + EP_KFIN))[r];
        float4 v = *((const float4*)(cb + (((size_t)k) << 8)) + lane);
        *((float4*)(out + (((size_t)(R0 + r)) << 8)) + lane) = v;
    }
    for (int t = tid; t < 1024; t += 512)
        atomicAdd(ws + WS_AVGP + t, epi[EP_AVGP + t]);
    if (tid < 64) {
        float sp = epi[EP_SP + tid];
        float dd = epi[EP_DFIN + tid];
#pragma unroll
        for (int off = 1; off <= 32; off <<= 1) {
            sp += __shfl_xor(sp, off, 64);
            dd += __shfl_xor(dd, off, 64);
        }
        if (tid == 0) {
            atomicAdd(ws + WS_PLP, sp);
            atomicAdd(ws + WS_DMIN, dd);
        }
    }
}

// ---------------- finalize ----------------
__global__ __launch_bounds__(256) void vq_finalize(const float* __restrict__ ws,
                                                   float* __restrict__ out) {
    __shared__ float red[4];
    int tid = threadIdx.x;
    float part = 0.f;
    for (int k = tid; k < 1024; k += 256) {
        float ap = ws[WS_AVGP + k] * (1.0f / 65536.0f);
        part += ap * logf(ap + 1e-5f);
    }
#pragma unroll
    for (int off = 32; off; off >>= 1) part += __shfl_xor(part, off, 64);
    if ((tid & 63) == 0) red[tid >> 6] = part;
    __syncthreads();
    if (tid == 0) {
        float sum_aplog      = red[0] + red[1] + red[2] + red[3];
        float avg_entropy    = -sum_aplog;
        float sample_entropy = -ws[WS_PLP] * (1.0f / 65536.0f);
        float entropy_loss   = (sample_entropy - avg_entropy) * 0.1f;
        float eq = 1.25f * ws[WS_DMIN] * (1.0f / ((float)NROWS * (float)DIM));
        out[QOFF] = eq + entropy_loss;
    }
}

extern "C" void kernel_launch(void* const* d_in, const int* in_sizes, int n_in,
                              void* d_out, int out_size, void* d_ws, size_t ws_size,
                              hipStream_t stream) {
    const float* x  = (const float*)d_in[0];
    const float* cb = (const float*)d_in[1];
    float* out = (float*)d_out;
    float* ws  = (float*)d_ws;

    hipMemsetAsync(d_ws, 0, WS_C2 * sizeof(float), stream);

    c2_kernel<<<KCB / 256, 256, 0, stream>>>(cb, ws);
    cvt_cb_kernel<<<256, 256, 0, stream>>>(cb, ws);

    hipFuncSetAttribute((const void*)vq_main,
                        hipFuncAttributeMaxDynamicSharedMemorySize, SMEM_BYTES);
    vq_main<<<NROWS / TM, 512, SMEM_BYTES, stream>>>(x, cb, ws, out);

    vq_finalize<<<1, 256, 0, stream>>>(ws, out);
}

// Round 4
// 351.344 us; speedup vs baseline: 2.4916x; 1.1344x over previous
//
#include <hip/hip_runtime.h>
#include <math.h>

#define NROWS 65536
#define DIM   256
#define KCB   1024
#define TM    32
#define NBLK  (NROWS / TM)     // 2048
#define QOFF  (NROWS * DIM)
#define IDXOFF (QOFF + 1)

// ws float layout
#define WS_DMIN 0
#define WS_PLP  1
#define WS_AVGP 4              // 1024 floats
#define WS_C2   1028           // 1024 floats
#define WS_CBF  2052           // fragment-ordered hi-bf16 codebook: 131072 ushort = 65536 floats

#define DELTA 0.05f

typedef __attribute__((ext_vector_type(8))) __bf16 bf16x8;
typedef __attribute__((ext_vector_type(4))) float  f32x4;
typedef __attribute__((ext_vector_type(8))) unsigned short u16x8;

// epilogue LDS float offsets (static shared, 3264 floats = 13056 B)
#define EP_REDD 0       // [8][32]
#define EP_REDK 256
#define EP_RT1  512
#define EP_RT2  768
#define EP_GMIN 1024    // 32
#define EP_CNT  1056    // 32
#define EP_CAND 1088    // 32*16
#define EP_CEX  1600    // 32*16
#define EP_R1F  2112    // 32
#define EP_SP   2144    // 32
#define EP_KFIN 2176    // 32
#define EP_DFIN 2208    // 32
#define EP_AVGP 2240    // 1024
#define EP_SIZE 3264

__device__ __forceinline__ unsigned short f2bf(float f) {
    unsigned u = __float_as_uint(f);
    u += 0x7fffu + ((u >> 16) & 1u);
    return (unsigned short)(u >> 16);
}

__device__ __forceinline__ bf16x8 cvt8(const float* src) {
    float4 v0 = *(const float4*)src, v1 = *(const float4*)(src + 4);
    u16x8 o;
    o[0] = f2bf(v0.x); o[1] = f2bf(v0.y); o[2] = f2bf(v0.z); o[3] = f2bf(v0.w);
    o[4] = f2bf(v1.x); o[5] = f2bf(v1.y); o[6] = f2bf(v1.z); o[7] = f2bf(v1.w);
    return __builtin_bit_cast(bf16x8, o);
}

// ---------------- prep: exact-grid c2 + fragment-ordered hi-bf16 codebook + ws zero ----------------
__global__ __launch_bounds__(256) void prep_kernel(const float* __restrict__ cb,
                                                   float* __restrict__ ws) {
    int k = blockIdx.x * 256 + threadIdx.x;   // 0..1023 (grid = 4)
    // zero accumulators (WS_DMIN..WS_AVGP region)
    if (k < 4) ws[k] = 0.f;
    ws[WS_AVGP + k] = 0.f;

    // c2 on the EXACT round-1 grid (sequential float4 chain)
    const float4* row = (const float4*)(cb + (size_t)k * DIM);
    float s = 0.f;
#pragma unroll 8
    for (int i = 0; i < DIM / 4; ++i) {
        float4 v = row[i];
        s += v.x * v.x + v.y * v.y + v.z * v.z + v.w * v.w;
    }
    ws[WS_C2 + k] = s;

    // fragment-ordered hi-bf16: chunk[((kc*1024 + k)*4 + q)] = bf16(cb[k][kc*32+q*8 .. +8])
    unsigned short* cbf = (unsigned short*)(ws + WS_CBF);
#pragma unroll
    for (int kc = 0; kc < 8; ++kc) {
#pragma unroll
        for (int q = 0; q < 4; ++q) {
            const float* src = cb + (size_t)k * DIM + (kc << 5) + (q << 3);
            u16x8 o;
#pragma unroll
            for (int j = 0; j < 8; ++j) o[j] = f2bf(src[j]);
            *(u16x8*)(cbf + ((((size_t)(kc << 10) + k) << 2) + q) * 8) = o;
        }
    }
}

// ---------------- main fused kernel: barrier-free K-loop, B streamed from L2 ----------------
__global__ __launch_bounds__(512, 4) void vq_main(const float* __restrict__ x,
                                                  const float* __restrict__ cb,
                                                  float* __restrict__ ws,
                                                  float* __restrict__ out) {
    __shared__ float epi[EP_SIZE];

    const int tid  = threadIdx.x;
    const int w    = tid >> 6;
    const int lane = tid & 63;
    const int m    = lane & 15;
    const int q    = lane >> 4;
    const int R0   = blockIdx.x * TM;

    const u16x8* cbf = (const u16x8*)(ws + WS_CBF);
    // chunk index = (kc*1024 + c)*4 + q, c = h*512 + w*64 + ct*16 + m
    const u16x8* bbase = cbf + (((w << 6) + m) << 2) + q;
    // steps in u16x8 units: kc: 4096, h: 2048, ct: 64

    f32x4 acc[2][8];
#pragma unroll
    for (int a = 0; a < 2; ++a)
#pragma unroll
        for (int b = 0; b < 8; ++b) acc[a][b] = (f32x4)0.f;

    u16x8 breg[2][4];
    bf16x8 ah[2];

    // prologue
    {
        const u16x8* p = bbase;  // sub 0: kc=0,h=0
        breg[0][0] = p[0]; breg[0][1] = p[64]; breg[0][2] = p[128]; breg[0][3] = p[192];
        ah[0] = cvt8(x + (size_t)(R0 + m) * DIM + (q << 3));
        ah[1] = cvt8(x + (size_t)(R0 + 16 + m) * DIM + (q << 3));
    }

#pragma unroll
    for (int sub = 0; sub < 16; ++sub) {
        const int pb = sub & 1;
        if (sub < 15) {
            const int ns = sub + 1;
            const u16x8* p = bbase + ((ns >> 1) << 12) + ((ns & 1) << 11);
            breg[pb ^ 1][0] = p[0];   breg[pb ^ 1][1] = p[64];
            breg[pb ^ 1][2] = p[128]; breg[pb ^ 1][3] = p[192];
        }
#pragma unroll
        for (int ct = 0; ct < 4; ++ct) {
            bf16x8 bh = __builtin_bit_cast(bf16x8, breg[pb][ct]);
            int cg = ((sub & 1) << 2) + ct;
            acc[0][cg] = __builtin_amdgcn_mfma_f32_16x16x32_bf16(ah[0], bh, acc[0][cg], 0, 0, 0);
            acc[1][cg] = __builtin_amdgcn_mfma_f32_16x16x32_bf16(ah[1], bh, acc[1][cg], 0, 0, 0);
        }
        // load+convert A for next kc during the odd sub (used two subs later)
        if ((sub & 1) == 1 && sub < 15) {
            const int nkc = (sub >> 1) + 1;
            ah[0] = cvt8(x + (size_t)(R0 + m) * DIM + (nkc << 5) + (q << 3));
            ah[1] = cvt8(x + (size_t)(R0 + 16 + m) * DIM + (nkc << 5) + (q << 3));
        }
    }

    // ================= epilogue (rows = 32) =================
    // E0: zero block accumulators; g = c2 - 2*acc (screen grid); per-wave per-row argmin
    if (tid < 32) ((int*)(epi + EP_CNT))[tid] = 0;
#pragma unroll
    for (int t = tid; t < 1024; t += 512) epi[EP_AVGP + t] = 0.f;

    float c2v[8];
#pragma unroll
    for (int cg = 0; cg < 8; ++cg) {
        int col = ((cg >> 2) << 9) + (w << 6) + ((cg & 3) << 4) + m;
        c2v[cg] = ws[WS_C2 + col];
    }
#pragma unroll
    for (int rt = 0; rt < 2; ++rt) {
#pragma unroll
        for (int reg = 0; reg < 4; ++reg) {
            int row = (rt << 4) + (q << 2) + reg;
            float md = 3.0e38f; int mk = 0;
#pragma unroll
            for (int cg = 0; cg < 8; ++cg) {
                float g = c2v[cg] - 2.0f * acc[rt][cg][reg];
                acc[rt][cg][reg] = g;
                int col = ((cg >> 2) << 9) + (w << 6) + ((cg & 3) << 4) + m;
                if (g < md) { md = g; mk = col; }
            }
#pragma unroll
            for (int off = 1; off <= 8; off <<= 1) {
                float od = __shfl_xor(md, off, 64);
                int   ok = __shfl_xor(mk, off, 64);
                if (od < md || (od == md && ok < mk)) { md = od; mk = ok; }
            }
            if (m == 0) {
                epi[EP_REDD + (w << 5) + row] = md;
                ((int*)(epi + EP_REDK))[(w << 5) + row] = mk;
            }
        }
    }
    __syncthreads();

    // E1: cross-wave min per row (screen grid: softmax shift + window reference)
    if (tid < 32) {
        float gm = 3.0e38f;
#pragma unroll
        for (int wv = 0; wv < 8; ++wv) {
            float d = epi[EP_REDD + (wv << 5) + tid];
            if (d < gm) gm = d;
        }
        epi[EP_GMIN + tid] = gm;
    }
    __syncthreads();

    // E2: exp pass + candidate collection + per-wave T1/T2
    {
        int* cnt  = (int*)(epi + EP_CNT);
        int* cand = (int*)(epi + EP_CAND);
#pragma unroll
        for (int rt = 0; rt < 2; ++rt) {
#pragma unroll
            for (int reg = 0; reg < 4; ++reg) {
                int row = (rt << 4) + (q << 2) + reg;
                float gm = epi[EP_GMIN + row];
                float t1 = 0.f, t2 = 0.f;
#pragma unroll
                for (int cg = 0; cg < 8; ++cg) {
                    float g = acc[rt][cg][reg];
                    if (g < gm + DELTA) {
                        int col = ((cg >> 2) << 9) + (w << 6) + ((cg & 3) << 4) + m;
                        int pos = atomicAdd(&cnt[row], 1);
                        if (pos < 16) cand[(row << 4) + pos] = col;
                    }
                    float z = -100.0f * (g - gm);
                    float e = __expf(z);
                    acc[rt][cg][reg] = e;
                    t1 += e;
                    t2 += e * z;
                }
#pragma unroll
                for (int off = 1; off <= 8; off <<= 1) {
                    t1 += __shfl_xor(t1, off, 64);
                    t2 += __shfl_xor(t2, off, 64);
                }
                if (m == 0) {
                    epi[EP_RT1 + (w << 5) + row] = t1;
                    epi[EP_RT2 + (w << 5) + row] = t2;
                }
            }
        }
    }
    __syncthreads();

    // E3: finalize per-row softmax stats
    if (tid < 32) {
        float T1 = 0.f, T2 = 0.f;
#pragma unroll
        for (int wv = 0; wv < 8; ++wv) {
            T1 += epi[EP_RT1 + (wv << 5) + tid];
            T2 += epi[EP_RT2 + (wv << 5) + tid];
        }
        float r1 = 1.0f / T1;
        epi[EP_R1F + tid] = r1;
        epi[EP_SP + tid]  = T2 * r1 - logf(T1);
    }
    __syncthreads();

    // E4a: avg_probs column sums (each wave owns its 64 cols per half -> no race)
    {
        float r1v[2][4];
#pragma unroll
        for (int rt = 0; rt < 2; ++rt)
#pragma unroll
            for (int reg = 0; reg < 4; ++reg)
                r1v[rt][reg] = epi[EP_R1F + (rt << 4) + (q << 2) + reg];
#pragma unroll
        for (int cg = 0; cg < 8; ++cg) {
            float s = 0.f;
#pragma unroll
            for (int rt = 0; rt < 2; ++rt)
#pragma unroll
                for (int reg = 0; reg < 4; ++reg)
                    s += acc[rt][cg][reg] * r1v[rt][reg];
            s += __shfl_xor(s, 16, 64);
            s += __shfl_xor(s, 32, 64);
            if (lane < 16) {
                int col = ((cg >> 2) << 9) + (w << 6) + ((cg & 3) << 4) + m;
                epi[EP_AVGP + col] += s;
            }
        }
    }
    // E4b: candidate refinement on the EXACT round-1/np grid:
    //      d = (x2 - 2*ab) + c2; ab sequential fmaf chain; x2 round-1 expression.
    {
        int* cnt  = (int*)(epi + EP_CNT);
        int* cand = (int*)(epi + EP_CAND);
        int r = tid >> 4;          // 16 threads per row
        int i = tid & 15;
        int n = cnt[r]; if (n > 16) n = 16;
        if (i < n) {
            int k = cand[(r << 4) + i];
            const float4* ax = (const float4*)(x  + (((size_t)(R0 + r)) << 8));
            const float4* bx = (const float4*)(cb + (((size_t)k) << 8));
            float ab = 0.f, x2 = 0.f;
            for (int d4 = 0; d4 < 64; ++d4) {
                float4 a = ax[d4], b = bx[d4];
                ab = fmaf(a.x, b.x, ab);
                ab = fmaf(a.y, b.y, ab);
                ab = fmaf(a.z, b.z, ab);
                ab = fmaf(a.w, b.w, ab);
                x2 += a.x * a.x + a.y * a.y + a.z * a.z + a.w * a.w;
            }
            float t = 2.0f * ab;
            epi[EP_CEX + (r << 4) + i] = (x2 - t) + ws[WS_C2 + k];
        }
    }
    __syncthreads();

    // E5: final per-row selection (min d, lowest-index tie-break) + index output
    if (tid < 32) {
        int* cnt  = (int*)(epi + EP_CNT);
        int* cand = (int*)(epi + EP_CAND);
        int n = cnt[tid]; if (n > 16) n = 16;
        float bd = epi[EP_CEX + (tid << 4)];
        int   bk = cand[(tid << 4)];
        for (int i = 1; i < n; ++i) {
            float d = epi[EP_CEX + (tid << 4) + i];
            int   k = cand[(tid << 4) + i];
            if (d < bd || (d == bd && k < bk)) { bd = d; bk = k; }
        }
        ((int*)(epi + EP_KFIN))[tid] = bk;
        epi[EP_DFIN + tid] = bd;
        out[IDXOFF + R0 + tid] = (float)bk;
    }
    __syncthreads();

    // E6: quantized gather (wave w -> rows w*4..w*4+3), global accumulators
#pragma unroll
    for (int rr = 0; rr < 4; ++rr) {
        int r = (w << 2) + rr;
        int k = ((int*)(epi + EP_KFIN))[r];
        float4 v = *((const float4*)(cb + (((size_t)k) << 8)) + lane);
        *((float4*)(out + (((size_t)(R0 + r)) << 8)) + lane) = v;
    }
    for (int t = tid; t < 1024; t += 512)
        atomicAdd(ws + WS_AVGP + t, epi[EP_AVGP + t]);
    if (tid < 32) {
        float sp = epi[EP_SP + tid];
        float dd = epi[EP_DFIN + tid];
#pragma unroll
        for (int off = 1; off <= 16; off <<= 1) {
            sp += __shfl_xor(sp, off, 64);
            dd += __shfl_xor(dd, off, 64);
        }
        if (tid == 0) {
            atomicAdd(ws + WS_PLP, sp);
            atomicAdd(ws + WS_DMIN, dd);
        }
    }
}

// ---------------- finalize ----------------
__global__ __launch_bounds__(256) void vq_finalize(const float* __restrict__ ws,
                                                   float* __restrict__ out) {
    __shared__ float red[4];
    int tid = threadIdx.x;
    float part = 0.f;
    for (int k = tid; k < 1024; k += 256) {
        float ap = ws[WS_AVGP + k] * (1.0f / 65536.0f);
        part += ap * logf(ap + 1e-5f);
    }
#pragma unroll
    for (int off = 32; off; off >>= 1) part += __shfl_xor(part, off, 64);
    if ((tid & 63) == 0) red[tid >> 6] = part;
    __syncthreads();
    if (tid == 0) {
        float sum_aplog      = red[0] + red[1] + red[2] + red[3];
        float avg_entropy    = -sum_aplog;
        float sample_entropy = -ws[WS_PLP] * (1.0f / 65536.0f);
        float entropy_loss   = (sample_entropy - avg_entropy) * 0.1f;
        float eq = 1.25f * ws[WS_DMIN] * (1.0f / ((float)NROWS * (float)DIM));
        out[QOFF] = eq + entropy_loss;
    }
}

extern "C" void kernel_launch(void* const* d_in, const int* in_sizes, int n_in,
                              void* d_out, int out_size, void* d_ws, size_t ws_size,
                              hipStream_t stream) {
    const float* x  = (const float*)d_in[0];
    const float* cb = (const float*)d_in[1];
    float* out = (float*)d_out;
    float* ws  = (float*)d_ws;

    prep_kernel<<<4, 256, 0, stream>>>(cb, ws);
    vq_main<<<NBLK, 512, 0, stream>>>(x, cb, ws, out);
    vq_finalize<<<1, 256, 0, stream>>>(ws, out);
}